// Round 10
// baseline (319.137 us; speedup 1.0000x reference)
//
#include <hip/hip_runtime.h>
#include <hip/hip_fp16.h>

#define BG 64
#define NN 2048
#define MM 2048
#define CC 64
#define HH 128
#define NNZE 32768
#define TH 384  // 3*H

// ---------------- prep phase A: per-(graph, quarter) counting, 256 blocks ----------------
__global__ __launch_bounds__(1024) void prep_count_kernel(const int* __restrict__ d_rows,
                                                          const int* __restrict__ d_index,
                                                          int* __restrict__ cnt_blk,
                                                          int* __restrict__ cnt_clu_blk) {
    __shared__ int cnt_row_s[MM];
    __shared__ int cnt_clu_s[CC];
    int gb = blockIdx.x;  // g*4 + b
    int g = gb >> 2, b = gb & 3;
    int t = threadIdx.x;
    cnt_row_s[t] = 0;
    cnt_row_s[t + 1024] = 0;
    if (t < CC) cnt_clu_s[t] = 0;
    __syncthreads();
    const int* rows_g = d_rows + ((size_t)g << 15) + (b << 13);
#pragma unroll
    for (int it = 0; it < 8; it++) atomicAdd(&cnt_row_s[rows_g[it * 1024 + t]], 1);
    if (t < 512) atomicAdd(&cnt_clu_s[d_index[(g << 11) + (b << 9) + t]], 1);
    __syncthreads();
    int* cb = cnt_blk + (size_t)gb * MM;
    cb[t] = cnt_row_s[t];
    cb[t + 1024] = cnt_row_s[t + 1024];
    if (t < CC) cnt_clu_blk[gb * CC + t] = cnt_clu_s[t];
}

// ---------------- prep phase B: per-graph scans, rlist, per-block base offsets ----------------
__global__ __launch_bounds__(1024) void prep_scan_kernel(const int* __restrict__ d_index,
                                                         const int* __restrict__ cnt_blk,
                                                         const int* __restrict__ cnt_clu_blk,
                                                         int* __restrict__ cnt_clu_g,
                                                         int* __restrict__ off_clu_g,
                                                         int* __restrict__ row_edge_off_g,
                                                         int* __restrict__ off_row_blk,
                                                         int* __restrict__ end_pos) {
    __shared__ int cnt_clu_s[CC], off_clu_s[CC], fill_clu_s[CC];
    __shared__ int rlist_s[MM];
    __shared__ int rowtot_s[MM];
    __shared__ int blk1_s[MM], blk2_s[MM], blk3_s[MM];
    __shared__ int off_row_s[MM];
    __shared__ int wsum[16];
    int g = blockIdx.x, t = threadIdx.x;
    int lane = t & 63, w = t >> 6;

    // row totals + per-block prefixes (coalesced)
    const int* cb = cnt_blk + ((size_t)g << 2) * MM;
    for (int r = t; r < MM; r += 1024) {
        int c0 = cb[r], c1 = cb[MM + r], c2 = cb[2 * MM + r], c3 = cb[3 * MM + r];
        blk1_s[r] = c0;
        blk2_s[r] = c0 + c1;
        blk3_s[r] = c0 + c1 + c2;
        rowtot_s[r] = c0 + c1 + c2 + c3;
    }
    // cluster counts + scan (wave 0)
    if (t < CC) {
        const int* ccb = cnt_clu_blk + (g << 2) * CC;
        int v = ccb[t] + ccb[CC + t] + ccb[2 * CC + t] + ccb[3 * CC + t];
        cnt_clu_s[t] = v;
        fill_clu_s[t] = 0;
        int incl = v;
#pragma unroll
        for (int d = 1; d < 64; d <<= 1) {
            int u = __shfl_up(incl, d);
            if (t >= d) incl += u;
        }
        off_clu_s[t] = incl - v;
        cnt_clu_g[(g << 6) + t] = v;
        off_clu_g[(g << 6) + t] = incl - v;
    }
    int idx0 = d_index[(g << 11) + t];
    int idx1 = d_index[(g << 11) + t + 1024];
    __syncthreads();

    // rlist: rows in cluster-major order
    {
        int s0 = atomicAdd(&fill_clu_s[idx0], 1);
        rlist_s[off_clu_s[idx0] + s0] = t;
        int s1 = atomicAdd(&fill_clu_s[idx1], 1);
        rlist_s[off_clu_s[idx1] + s1] = t + 1024;
    }
    __syncthreads();

    // cluster-major scan of row totals (thread t owns j=2t, 2t+1)
    int r0 = rlist_s[2 * t], r1 = rlist_s[2 * t + 1];
    int c0 = rowtot_s[r0], c1 = rowtot_s[r1];
    int s = c0 + c1;
    int incl = s;
#pragma unroll
    for (int d = 1; d < 64; d <<= 1) {
        int u = __shfl_up(incl, d);
        if (lane >= d) incl += u;
    }
    if (lane == 63) wsum[w] = incl;
    __syncthreads();
    if (t < 16) {
        int v = wsum[t], iv = v;
#pragma unroll
        for (int d = 1; d < 16; d <<= 1) {
            int u = __shfl_up(iv, d);
            if (t >= d) iv += u;
        }
        wsum[t] = iv - v;  // exclusive
    }
    __syncthreads();
    {
        int base = wsum[w] + incl - s;
        int* reo = row_edge_off_g + g * (MM + 1);
        reo[2 * t] = base;
        reo[2 * t + 1] = base + c0;
        off_row_s[r0] = base;
        off_row_s[r1] = base + c0;
        if (t == 0) reo[MM] = NNZE;
    }
    __syncthreads();

    // emit per-(block,row) bases + end positions (coalesced by r)
    int* ob = off_row_blk + ((size_t)g << 2) * MM;
    int* epp = end_pos + (size_t)g * MM;
    for (int r = t; r < MM; r += 1024) {
        int orr = off_row_s[r];
        ob[r] = orr;
        ob[MM + r] = orr + blk1_s[r];
        ob[2 * MM + r] = orr + blk2_s[r];
        ob[3 * MM + r] = orr + blk3_s[r];
        epp[r] = orr + rowtot_s[r];
    }
}

// ---------------- fused phase C: cvt_x (blocks 0..2047) || prep_bin (blocks 2048..2303) ----------------
// independent work overlapped in one dispatch; cvt writes xh XCD-aligned (graph g on XCD g>>3)
// right before spmm so its L2 lines stay warm; bin's epack scatter uses nontemporal stores
// (packed as long long -- __builtin_nontemporal_store rejects HIP vector types)
// so the 16 MB stream doesn't evict xh.
__global__ __launch_bounds__(1024) void cvt_bin_kernel(const float* __restrict__ x,
                                                       uint* __restrict__ xh,
                                                       const int* __restrict__ d_rows,
                                                       const int* __restrict__ d_cols,
                                                       const float* __restrict__ d_vals,
                                                       const int* __restrict__ off_row_blk,
                                                       const int* __restrict__ end_pos,
                                                       long long* __restrict__ epack) {
    int bid = blockIdx.x;
    int t = threadIdx.x;
    if (bid < 2048) {
        // ---- cvt: 32 blocks per graph, XCD = bid&7 hosts graphs 8q..8q+7 ----
        int j = bid >> 3;                        // 0..255
        int g = ((bid & 7) << 3) + (j >> 5);     // XCD = bid&7 = g>>3
        int chunk = j & 31;
        int tid = g * 32768 + chunk * 1024 + t;  // group-of-8-floats index
        const float4* x4 = (const float4*)x;
        float4 a = x4[2 * tid], b = x4[2 * tid + 1];
        __half2 h0 = __float22half2_rn(make_float2(a.x, a.y));
        __half2 h1 = __float22half2_rn(make_float2(a.z, a.w));
        __half2 h2 = __float22half2_rn(make_float2(b.x, b.y));
        __half2 h3 = __float22half2_rn(make_float2(b.z, b.w));
        uint4 o;
        o.x = *(uint*)&h0;
        o.y = *(uint*)&h1;
        o.z = *(uint*)&h2;
        o.w = *(uint*)&h3;
        ((uint4*)xh)[tid] = o;
        return;
    }
    // ---- bin: each block owns pre-reserved sub-ranges -> LDS-only slot allocation ----
    __shared__ int off_s[MM];
    __shared__ int end_s[MM];
    __shared__ int fill_s[MM];
    int gb = bid - 2048;
    int g = gb >> 2, b = gb & 3;
    const int* ob = off_row_blk + (size_t)gb * MM;
    const int* epp = end_pos + (size_t)g * MM;
    off_s[t] = ob[t];
    off_s[t + 1024] = ob[t + 1024];
    end_s[t] = epp[t];
    end_s[t + 1024] = epp[t + 1024];
    fill_s[t] = 0;
    fill_s[t + 1024] = 0;
    __syncthreads();
    const int* rows_g = d_rows + ((size_t)g << 15) + (b << 13);
    const int* cols_g = d_cols + ((size_t)g << 15) + (b << 13);
    const float* vals_g = d_vals + ((size_t)g << 15) + (b << 13);
    long long* epg = epack + ((size_t)g << 15);
#pragma unroll
    for (int it = 0; it < 8; it++) {
        int e = it * 1024 + t;
        int r = rows_g[e];
        int slot = atomicAdd(&fill_s[r], 1);
        int pos = off_s[r] + slot;
        int flag = (pos == end_s[r] - 1) ? (int)0x80000000 : 0;
        unsigned int lo = (unsigned int)(cols_g[e] | flag);
        unsigned int hi = (unsigned int)__float_as_int(vals_g[e]);
        long long pk = (long long)(((unsigned long long)hi << 32) | lo);
        __builtin_nontemporal_store(pk, &epg[pos]);
    }
}

// ---------------- fused SpMM + mean/max/sum pooling, one wave64 per cluster, fp16 x ----------------
// lane h handles features 2h,2h+1: one uint gather per lane -> 256 B/row coalesced (R6 shape:
// 64-thr blocks measured 60us vs 256-thr 93us -- TA-throughput-bound, more waves don't help)
__global__ __launch_bounds__(64) void spmm_pool_kernel(const uint* __restrict__ xh,
                                                       const int* __restrict__ cnt_clu,
                                                       const int* __restrict__ off_clu,
                                                       const int* __restrict__ row_edge_off,
                                                       const long long* __restrict__ epack,
                                                       float* __restrict__ xdec) {
    // XCD-aware swizzle: bid&7 -> XCD, graphs [8q, 8q+7] on XCD q (matches cvt)
    int bid = blockIdx.x;
    int l = bid >> 3;
    int g = ((bid & 7) << 3) + (l >> 6);
    int c = l & 63;
    int h = threadIdx.x;  // 0..63
    int gc = (g << 6) + c;
    int rcnt = cnt_clu[gc];
    int j0 = off_clu[gc];
    const int* reo = row_edge_off + g * (MM + 1) + j0;
    int ebase = reo[0];
    int etot = reo[rcnt] - ebase;
    const long long* ep = epack + ((size_t)g << 15) + ebase;
    const uint* xg = xh + ((size_t)g << 17);  // g*N*(H/2) uints
    float2 coef = make_float2(0.f, 0.f), sum = make_float2(0.f, 0.f);
    float2 mx = make_float2(-__builtin_inff(), -__builtin_inff());
    int e = 0;
    for (; e + 16 <= etot; e += 16) {
        long long q[16];
#pragma unroll
        for (int k = 0; k < 16; k++) q[k] = __builtin_nontemporal_load(&ep[e + k]);
        uint xv[16];
#pragma unroll
        for (int k = 0; k < 16; k++)
            xv[k] = xg[(((uint)(int)q[k] & 0x7FFFFFFFu) << 6) + h];
#pragma unroll
        for (int k = 0; k < 16; k++) {
            float v = __int_as_float((int)(q[k] >> 32));
            float2 f = __half22float2(*(__half2*)&xv[k]);
            coef.x = fmaf(v, f.x, coef.x);
            coef.y = fmaf(v, f.y, coef.y);
            if ((int)q[k] < 0) {  // wave-uniform (all lanes see same edge)
                sum.x += coef.x; sum.y += coef.y;
                mx.x = fmaxf(mx.x, coef.x); mx.y = fmaxf(mx.y, coef.y);
                coef.x = 0.f; coef.y = 0.f;
            }
        }
    }
    for (; e < etot; e++) {
        long long q = ep[e];
        uint xv = xg[(((uint)(int)q & 0x7FFFFFFFu) << 6) + h];
        float v = __int_as_float((int)(q >> 32));
        float2 f = __half22float2(*(__half2*)&xv);
        coef.x = fmaf(v, f.x, coef.x);
        coef.y = fmaf(v, f.y, coef.y);
        if ((int)q < 0) {
            sum.x += coef.x; sum.y += coef.y;
            mx.x = fmaxf(mx.x, coef.x); mx.y = fmaxf(mx.y, coef.y);
            coef.x = 0.f; coef.y = 0.f;
        }
    }
    // rows with zero edges contribute coef==0 to the max
    int az = 0;
    for (int j = h; j < rcnt; j += 64) az |= (reo[j + 1] == reo[j]);
    if (__ballot(az) != 0ULL) {
        mx.x = fmaxf(mx.x, 0.f);
        mx.y = fmaxf(mx.y, 0.f);
    }
    float inv = 1.f / (float)(rcnt > 0 ? rcnt : 1);
    float* xd = xdec + (size_t)gc * TH;
    *(float2*)&xd[2 * h] = make_float2(sum.x * inv, sum.y * inv);
    *(float2*)&xd[HH + 2 * h] = mx;
    *(float2*)&xd[2 * HH + 2 * h] = sum;
}

// ---------------- QKV projection: [4096,384] @ [384,384] -> QKV [4096,384] ----------------
__global__ __launch_bounds__(256) void qkv_kernel(const float* __restrict__ xdec,
                                                  const float* __restrict__ Wq,
                                                  const float* __restrict__ Wk,
                                                  const float* __restrict__ Wv,
                                                  float* __restrict__ QKV) {
    __shared__ float As[16][68];  // A^T tile: [k][row], pad avoids bank conflicts
    __shared__ float Bs[16][64];  // [k][col]
    int bx = blockIdx.x, by = blockIdx.y;
    int t = threadIdx.x;
    int tx = t & 15, ty = t >> 4;
    const float* W = (by < 2) ? Wq : (by < 4) ? Wk : Wv;
    int cbase = (by & 1) * 64;
    int r0 = bx * 64;
    float acc[4][4] = {};
    int lrow = t >> 2, lk4 = (t & 3) * 4;
    for (int k0 = 0; k0 < TH; k0 += 16) {
        float4 av = *(const float4*)&xdec[(size_t)(r0 + lrow) * TH + k0 + lk4];
        As[lk4][lrow] = av.x;
        As[lk4 + 1][lrow] = av.y;
        As[lk4 + 2][lrow] = av.z;
        As[lk4 + 3][lrow] = av.w;
        *(float4*)&Bs[ty][tx * 4] = *(const float4*)&W[(size_t)(k0 + ty) * HH + cbase + tx * 4];
        __syncthreads();
#pragma unroll
        for (int k = 0; k < 16; k++) {
            float4 a = *(float4*)&As[k][ty * 4];
            float4 b = *(float4*)&Bs[k][tx * 4];
            float ar[4] = {a.x, a.y, a.z, a.w};
            float br[4] = {b.x, b.y, b.z, b.w};
#pragma unroll
            for (int i = 0; i < 4; i++)
#pragma unroll
                for (int j = 0; j < 4; j++) acc[i][j] = fmaf(ar[i], br[j], acc[i][j]);
        }
        __syncthreads();
    }
#pragma unroll
    for (int i = 0; i < 4; i++) {
        *(float4*)&QKV[(size_t)(r0 + ty * 4 + i) * TH + by * 64 + tx * 4] =
            make_float4(acc[i][0], acc[i][1], acc[i][2], acc[i][3]);
    }
}

// ---------------- per-graph 64x64 attention ----------------
__global__ __launch_bounds__(256) void attn_kernel(const float* __restrict__ QKV,
                                                   float* __restrict__ out) {
    __shared__ float Qs[16][132];
    __shared__ float sc[16][68];
    int g = blockIdx.x;
    int q0 = blockIdx.y * 16;
    int t = threadIdx.x;
    const float* base = QKV + (size_t)(g * CC) * TH;
    for (int u = t; u < 512; u += 256) {
        int i = u >> 5, cc = u & 31;
        *(float4*)&Qs[i][cc * 4] = *(const float4*)&base[(size_t)(q0 + i) * TH + cc * 4];
    }
    __syncthreads();
    {  // scores: thread (iq, j) computes rows iq, iq+4, iq+8, iq+12 vs col j
        int j = t & 63, iq = t >> 6;
        float a0 = 0, a1 = 0, a2 = 0, a3 = 0;
        const float* Krow = base + (size_t)j * TH + HH;
#pragma unroll 4
        for (int cc = 0; cc < 32; cc++) {
            float4 kv = *(const float4*)&Krow[cc * 4];
            float4 q0v = *(float4*)&Qs[iq][cc * 4];
            float4 q1v = *(float4*)&Qs[4 + iq][cc * 4];
            float4 q2v = *(float4*)&Qs[8 + iq][cc * 4];
            float4 q3v = *(float4*)&Qs[12 + iq][cc * 4];
            a0 += kv.x * q0v.x + kv.y * q0v.y + kv.z * q0v.z + kv.w * q0v.w;
            a1 += kv.x * q1v.x + kv.y * q1v.y + kv.z * q1v.z + kv.w * q1v.w;
            a2 += kv.x * q2v.x + kv.y * q2v.y + kv.z * q2v.z + kv.w * q2v.w;
            a3 += kv.x * q3v.x + kv.y * q3v.y + kv.z * q3v.z + kv.w * q3v.w;
        }
        const float scale = 0.08838834764831845f;  // 1/sqrt(128)
        sc[iq][j] = a0 * scale;
        sc[4 + iq][j] = a1 * scale;
        sc[8 + iq][j] = a2 * scale;
        sc[12 + iq][j] = a3 * scale;
    }
    __syncthreads();
    {  // softmax: 16 threads per row, 4 cols each
        int i = t >> 4, l = t & 15;
        float4 sv = *(float4*)&sc[i][l * 4];
        float m = fmaxf(fmaxf(sv.x, sv.y), fmaxf(sv.z, sv.w));
#pragma unroll
        for (int d = 1; d < 16; d <<= 1) m = fmaxf(m, __shfl_xor(m, d));
        float4 p;
        p.x = __expf(sv.x - m);
        p.y = __expf(sv.y - m);
        p.z = __expf(sv.z - m);
        p.w = __expf(sv.w - m);
        float s = p.x + p.y + p.z + p.w;
#pragma unroll
        for (int d = 1; d < 16; d <<= 1) s += __shfl_xor(s, d);
        float inv = 1.0f / s;
        p.x *= inv; p.y *= inv; p.z *= inv; p.w *= inv;
        *(float4*)&sc[i][l * 4] = p;
    }
    __syncthreads();
    {  // PV: thread (i, hq) computes out[i][hq*8 .. +8)
        int i = t >> 4, hq = t & 15;
        const float* Vbase = base + 2 * HH;
        float acc[8] = {};
        for (int j = 0; j < 64; j++) {
            float d = sc[i][j];
            float4 v0 = *(const float4*)&Vbase[(size_t)j * TH + hq * 8];
            float4 v1 = *(const float4*)&Vbase[(size_t)j * TH + hq * 8 + 4];
            acc[0] = fmaf(d, v0.x, acc[0]);
            acc[1] = fmaf(d, v0.y, acc[1]);
            acc[2] = fmaf(d, v0.z, acc[2]);
            acc[3] = fmaf(d, v0.w, acc[3]);
            acc[4] = fmaf(d, v1.x, acc[4]);
            acc[5] = fmaf(d, v1.y, acc[5]);
            acc[6] = fmaf(d, v1.z, acc[6]);
            acc[7] = fmaf(d, v1.w, acc[7]);
        }
        float* op = out + (size_t)g * (CC * HH) + (size_t)(q0 + i) * HH + hq * 8;
        *(float4*)&op[0] = make_float4(acc[0], acc[1], acc[2], acc[3]);
        *(float4*)&op[4] = make_float4(acc[4], acc[5], acc[6], acc[7]);
    }
}

extern "C" void kernel_launch(void* const* d_in, const int* in_sizes, int n_in,
                              void* d_out, int out_size, void* d_ws, size_t ws_size,
                              hipStream_t stream) {
    const float* x = (const float*)d_in[0];
    // d_in[1] = batch (unused: nodes sorted, equal graph sizes), d_in[2] = batch_size (compile-time 64)
    const int* d_rows = (const int*)d_in[3];
    const int* d_cols = (const int*)d_in[4];
    const float* d_vals = (const float*)d_in[5];
    const int* d_index = (const int*)d_in[6];
    const float* Wq = (const float*)d_in[7];
    const float* Wk = (const float*)d_in[8];
    const float* Wv = (const float*)d_in[9];
    float* out = (float*)d_out;

    char* ws = (char*)d_ws;
    size_t o = 0;
    uint* xh = (uint*)(ws + o); o += (size_t)BG * NN * (HH / 2) * 4;  // 32 MB fp16 x
    long long* epack = (long long*)(ws + o); o += (size_t)BG * NNZE * 8;  // 16 MB
    int* cnt_blk = (int*)(ws + o); o += (size_t)BG * 4 * MM * 4;      // 2 MB
    int* off_row_blk = (int*)(ws + o); o += (size_t)BG * 4 * MM * 4;  // 2 MB
    int* end_pos = (int*)(ws + o); o += (size_t)BG * MM * 4;
    int* cnt_clu_blk = (int*)(ws + o); o += (size_t)BG * 4 * CC * 4;
    int* row_edge_off = (int*)(ws + o); o += (size_t)BG * (MM + 1) * 4;
    int* cnt_clu = (int*)(ws + o); o += (size_t)BG * CC * 4;
    int* off_clu = (int*)(ws + o); o += (size_t)BG * CC * 4;
    float* xdec = (float*)(ws + o); o += (size_t)BG * CC * TH * 4;
    float* QKV = (float*)(ws + o); o += (size_t)BG * CC * TH * 4;

    prep_count_kernel<<<BG * 4, 1024, 0, stream>>>(d_rows, d_index, cnt_blk, cnt_clu_blk);
    prep_scan_kernel<<<BG, 1024, 0, stream>>>(d_index, cnt_blk, cnt_clu_blk,
                                              cnt_clu, off_clu, row_edge_off,
                                              off_row_blk, end_pos);
    cvt_bin_kernel<<<2048 + BG * 4, 1024, 0, stream>>>(x, xh, d_rows, d_cols, d_vals,
                                                       off_row_blk, end_pos, epack);
    spmm_pool_kernel<<<BG * CC, 64, 0, stream>>>(xh, cnt_clu, off_clu, row_edge_off,
                                                 epack, xdec);
    qkv_kernel<<<dim3(64, 6), 256, 0, stream>>>(xdec, Wq, Wk, Wv, QKV);
    attn_kernel<<<dim3(BG, 4), 256, 0, stream>>>(QKV, out);
}

// Round 11
// 272.823 us; speedup vs baseline: 1.1698x; 1.1698x over previous
//
#include <hip/hip_runtime.h>
#include <hip/hip_fp16.h>

#define BG 64
#define NN 2048
#define MM 2048
#define CC 64
#define HH 128
#define NNZE 32768
#define TH 384  // 3*H

// ---------------- x (fp32) -> xh (fp16 RNE), packed 2 features per uint ----------------
// XCD-swizzled to match spmm's graph->XCD mapping (graph g on XCD g>>3) and launched
// immediately before spmm: write-allocated L2 lines (4 MB/XCD) stay warm for the gather.
// [R8 evidence: spmm FETCH 52->34 MB with this ordering+swizzle]
__global__ __launch_bounds__(256) void cvt_x_kernel(const float* __restrict__ x,
                                                    uint* __restrict__ xh) {
    int bid = blockIdx.x;                       // 8192 blocks, 128 per graph
    int j = bid >> 3;                           // 0..1023
    int g = ((bid & 7) << 3) + (j >> 7);        // XCD = bid&7 = g>>3
    int chunk = j & 127;
    int tid = g * 32768 + chunk * 256 + threadIdx.x;  // group-of-8-floats index
    const float4* x4 = (const float4*)x;
    float4 a = x4[2 * tid], b = x4[2 * tid + 1];
    __half2 h0 = __float22half2_rn(make_float2(a.x, a.y));
    __half2 h1 = __float22half2_rn(make_float2(a.z, a.w));
    __half2 h2 = __float22half2_rn(make_float2(b.x, b.y));
    __half2 h3 = __float22half2_rn(make_float2(b.z, b.w));
    uint4 o;
    o.x = *(uint*)&h0;
    o.y = *(uint*)&h1;
    o.z = *(uint*)&h2;
    o.w = *(uint*)&h3;
    ((uint4*)xh)[tid] = o;
}

// ---------------- prep phase A: per-(graph, quarter) counting, 256 blocks ----------------
__global__ __launch_bounds__(1024) void prep_count_kernel(const int* __restrict__ d_rows,
                                                          const int* __restrict__ d_index,
                                                          int* __restrict__ cnt_blk,
                                                          int* __restrict__ cnt_clu_blk) {
    __shared__ int cnt_row_s[MM];
    __shared__ int cnt_clu_s[CC];
    int gb = blockIdx.x;  // g*4 + b
    int g = gb >> 2, b = gb & 3;
    int t = threadIdx.x;
    cnt_row_s[t] = 0;
    cnt_row_s[t + 1024] = 0;
    if (t < CC) cnt_clu_s[t] = 0;
    __syncthreads();
    const int* rows_g = d_rows + ((size_t)g << 15) + (b << 13);
#pragma unroll
    for (int it = 0; it < 8; it++) atomicAdd(&cnt_row_s[rows_g[it * 1024 + t]], 1);
    if (t < 512) atomicAdd(&cnt_clu_s[d_index[(g << 11) + (b << 9) + t]], 1);
    __syncthreads();
    int* cb = cnt_blk + (size_t)gb * MM;
    cb[t] = cnt_row_s[t];
    cb[t + 1024] = cnt_row_s[t + 1024];
    if (t < CC) cnt_clu_blk[gb * CC + t] = cnt_clu_s[t];
}

// ---------------- prep phase B: per-graph scans, rlist, per-block base offsets ----------------
__global__ __launch_bounds__(1024) void prep_scan_kernel(const int* __restrict__ d_index,
                                                         const int* __restrict__ cnt_blk,
                                                         const int* __restrict__ cnt_clu_blk,
                                                         int* __restrict__ cnt_clu_g,
                                                         int* __restrict__ off_clu_g,
                                                         int* __restrict__ row_edge_off_g,
                                                         int* __restrict__ off_row_blk,
                                                         int* __restrict__ end_pos) {
    __shared__ int cnt_clu_s[CC], off_clu_s[CC], fill_clu_s[CC];
    __shared__ int rlist_s[MM];
    __shared__ int rowtot_s[MM];
    __shared__ int blk1_s[MM], blk2_s[MM], blk3_s[MM];
    __shared__ int off_row_s[MM];
    __shared__ int wsum[16];
    int g = blockIdx.x, t = threadIdx.x;
    int lane = t & 63, w = t >> 6;

    // row totals + per-block prefixes (coalesced)
    const int* cb = cnt_blk + ((size_t)g << 2) * MM;
    for (int r = t; r < MM; r += 1024) {
        int c0 = cb[r], c1 = cb[MM + r], c2 = cb[2 * MM + r], c3 = cb[3 * MM + r];
        blk1_s[r] = c0;
        blk2_s[r] = c0 + c1;
        blk3_s[r] = c0 + c1 + c2;
        rowtot_s[r] = c0 + c1 + c2 + c3;
    }
    // cluster counts + scan (wave 0)
    if (t < CC) {
        const int* ccb = cnt_clu_blk + (g << 2) * CC;
        int v = ccb[t] + ccb[CC + t] + ccb[2 * CC + t] + ccb[3 * CC + t];
        cnt_clu_s[t] = v;
        fill_clu_s[t] = 0;
        int incl = v;
#pragma unroll
        for (int d = 1; d < 64; d <<= 1) {
            int u = __shfl_up(incl, d);
            if (t >= d) incl += u;
        }
        off_clu_s[t] = incl - v;
        cnt_clu_g[(g << 6) + t] = v;
        off_clu_g[(g << 6) + t] = incl - v;
    }
    int idx0 = d_index[(g << 11) + t];
    int idx1 = d_index[(g << 11) + t + 1024];
    __syncthreads();

    // rlist: rows in cluster-major order
    {
        int s0 = atomicAdd(&fill_clu_s[idx0], 1);
        rlist_s[off_clu_s[idx0] + s0] = t;
        int s1 = atomicAdd(&fill_clu_s[idx1], 1);
        rlist_s[off_clu_s[idx1] + s1] = t + 1024;
    }
    __syncthreads();

    // cluster-major scan of row totals (thread t owns j=2t, 2t+1)
    int r0 = rlist_s[2 * t], r1 = rlist_s[2 * t + 1];
    int c0 = rowtot_s[r0], c1 = rowtot_s[r1];
    int s = c0 + c1;
    int incl = s;
#pragma unroll
    for (int d = 1; d < 64; d <<= 1) {
        int u = __shfl_up(incl, d);
        if (lane >= d) incl += u;
    }
    if (lane == 63) wsum[w] = incl;
    __syncthreads();
    if (t < 16) {
        int v = wsum[t], iv = v;
#pragma unroll
        for (int d = 1; d < 16; d <<= 1) {
            int u = __shfl_up(iv, d);
            if (t >= d) iv += u;
        }
        wsum[t] = iv - v;  // exclusive
    }
    __syncthreads();
    {
        int base = wsum[w] + incl - s;
        int* reo = row_edge_off_g + g * (MM + 1);
        reo[2 * t] = base;
        reo[2 * t + 1] = base + c0;
        off_row_s[r0] = base;
        off_row_s[r1] = base + c0;
        if (t == 0) reo[MM] = NNZE;
    }
    __syncthreads();

    // emit per-(block,row) bases + end positions (coalesced by r)
    int* ob = off_row_blk + ((size_t)g << 2) * MM;
    int* epp = end_pos + (size_t)g * MM;
    for (int r = t; r < MM; r += 1024) {
        int orr = off_row_s[r];
        ob[r] = orr;
        ob[MM + r] = orr + blk1_s[r];
        ob[2 * MM + r] = orr + blk2_s[r];
        ob[3 * MM + r] = orr + blk3_s[r];
        epp[r] = orr + rowtot_s[r];
    }
}

// ---------------- prep phase C: per-(graph, quarter) binning, 256 blocks ----------------
// each block owns pre-reserved sub-ranges -> LDS-only slot allocation; flag is position-based.
// Plain (write-back) stores: nt-hint on scattered 8B stores caused 4x write amplification (R9).
__global__ __launch_bounds__(1024) void prep_bin_kernel(const int* __restrict__ d_rows,
                                                        const int* __restrict__ d_cols,
                                                        const float* __restrict__ d_vals,
                                                        const int* __restrict__ off_row_blk,
                                                        const int* __restrict__ end_pos,
                                                        int2* __restrict__ epack) {
    __shared__ int off_s[MM];
    __shared__ int end_s[MM];
    __shared__ int fill_s[MM];
    int gb = blockIdx.x;
    int g = gb >> 2, b = gb & 3;
    int t = threadIdx.x;
    const int* ob = off_row_blk + (size_t)gb * MM;
    const int* epp = end_pos + (size_t)g * MM;
    off_s[t] = ob[t];
    off_s[t + 1024] = ob[t + 1024];
    end_s[t] = epp[t];
    end_s[t + 1024] = epp[t + 1024];
    fill_s[t] = 0;
    fill_s[t + 1024] = 0;
    __syncthreads();
    const int* rows_g = d_rows + ((size_t)g << 15) + (b << 13);
    const int* cols_g = d_cols + ((size_t)g << 15) + (b << 13);
    const float* vals_g = d_vals + ((size_t)g << 15) + (b << 13);
    int2* epg = epack + ((size_t)g << 15);
#pragma unroll
    for (int it = 0; it < 8; it++) {
        int e = it * 1024 + t;
        int r = rows_g[e];
        int slot = atomicAdd(&fill_s[r], 1);
        int pos = off_s[r] + slot;
        int flag = (pos == end_s[r] - 1) ? (int)0x80000000 : 0;
        epg[pos] = make_int2(cols_g[e] | flag, __float_as_int(vals_g[e]));
    }
}

// ---------------- fused SpMM + mean/max/sum pooling, one wave64 per cluster, fp16 x ----------------
// lane h handles features 2h,2h+1: one uint gather per lane -> 256 B/row coalesced (R6 shape:
// 64-thr blocks measured 60us vs 256-thr 93us -- TA-throughput-bound, more waves don't help)
__global__ __launch_bounds__(64) void spmm_pool_kernel(const uint* __restrict__ xh,
                                                       const int* __restrict__ cnt_clu,
                                                       const int* __restrict__ off_clu,
                                                       const int* __restrict__ row_edge_off,
                                                       const int2* __restrict__ epack,
                                                       float* __restrict__ xdec) {
    // XCD-aware swizzle: bid&7 -> XCD, graphs [8q, 8q+7] on XCD q (matches cvt_x)
    int bid = blockIdx.x;
    int l = bid >> 3;
    int g = ((bid & 7) << 3) + (l >> 6);
    int c = l & 63;
    int h = threadIdx.x;  // 0..63
    int gc = (g << 6) + c;
    int rcnt = cnt_clu[gc];
    int j0 = off_clu[gc];
    const int* reo = row_edge_off + g * (MM + 1) + j0;
    int ebase = reo[0];
    int etot = reo[rcnt] - ebase;
    const long long* ep = (const long long*)(epack + ((size_t)g << 15)) + ebase;
    const uint* xg = xh + ((size_t)g << 17);  // g*N*(H/2) uints
    float2 coef = make_float2(0.f, 0.f), sum = make_float2(0.f, 0.f);
    float2 mx = make_float2(-__builtin_inff(), -__builtin_inff());
    int e = 0;
    for (; e + 16 <= etot; e += 16) {
        long long q[16];
#pragma unroll
        for (int k = 0; k < 16; k++) q[k] = __builtin_nontemporal_load(&ep[e + k]);
        uint xv[16];
#pragma unroll
        for (int k = 0; k < 16; k++)
            xv[k] = xg[(((uint)(int)q[k] & 0x7FFFFFFFu) << 6) + h];
#pragma unroll
        for (int k = 0; k < 16; k++) {
            float v = __int_as_float((int)(q[k] >> 32));
            float2 f = __half22float2(*(__half2*)&xv[k]);
            coef.x = fmaf(v, f.x, coef.x);
            coef.y = fmaf(v, f.y, coef.y);
            if ((int)q[k] < 0) {  // wave-uniform (all lanes see same edge)
                sum.x += coef.x; sum.y += coef.y;
                mx.x = fmaxf(mx.x, coef.x); mx.y = fmaxf(mx.y, coef.y);
                coef.x = 0.f; coef.y = 0.f;
            }
        }
    }
    for (; e < etot; e++) {
        long long q = ep[e];
        uint xv = xg[(((uint)(int)q & 0x7FFFFFFFu) << 6) + h];
        float v = __int_as_float((int)(q >> 32));
        float2 f = __half22float2(*(__half2*)&xv);
        coef.x = fmaf(v, f.x, coef.x);
        coef.y = fmaf(v, f.y, coef.y);
        if ((int)q < 0) {
            sum.x += coef.x; sum.y += coef.y;
            mx.x = fmaxf(mx.x, coef.x); mx.y = fmaxf(mx.y, coef.y);
            coef.x = 0.f; coef.y = 0.f;
        }
    }
    // rows with zero edges contribute coef==0 to the max
    int az = 0;
    for (int j = h; j < rcnt; j += 64) az |= (reo[j + 1] == reo[j]);
    if (__ballot(az) != 0ULL) {
        mx.x = fmaxf(mx.x, 0.f);
        mx.y = fmaxf(mx.y, 0.f);
    }
    float inv = 1.f / (float)(rcnt > 0 ? rcnt : 1);
    float* xd = xdec + (size_t)gc * TH;
    *(float2*)&xd[2 * h] = make_float2(sum.x * inv, sum.y * inv);
    *(float2*)&xd[HH + 2 * h] = mx;
    *(float2*)&xd[2 * HH + 2 * h] = sum;
}

// ---------------- QKV projection: [4096,384] @ [384,384] -> QKV [4096,384] ----------------
__global__ __launch_bounds__(256) void qkv_kernel(const float* __restrict__ xdec,
                                                  const float* __restrict__ Wq,
                                                  const float* __restrict__ Wk,
                                                  const float* __restrict__ Wv,
                                                  float* __restrict__ QKV) {
    __shared__ float As[16][68];  // A^T tile: [k][row], pad avoids bank conflicts
    __shared__ float Bs[16][64];  // [k][col]
    int bx = blockIdx.x, by = blockIdx.y;
    int t = threadIdx.x;
    int tx = t & 15, ty = t >> 4;
    const float* W = (by < 2) ? Wq : (by < 4) ? Wk : Wv;
    int cbase = (by & 1) * 64;
    int r0 = bx * 64;
    float acc[4][4] = {};
    int lrow = t >> 2, lk4 = (t & 3) * 4;
    for (int k0 = 0; k0 < TH; k0 += 16) {
        float4 av = *(const float4*)&xdec[(size_t)(r0 + lrow) * TH + k0 + lk4];
        As[lk4][lrow] = av.x;
        As[lk4 + 1][lrow] = av.y;
        As[lk4 + 2][lrow] = av.z;
        As[lk4 + 3][lrow] = av.w;
        *(float4*)&Bs[ty][tx * 4] = *(const float4*)&W[(size_t)(k0 + ty) * HH + cbase + tx * 4];
        __syncthreads();
#pragma unroll
        for (int k = 0; k < 16; k++) {
            float4 a = *(float4*)&As[k][ty * 4];
            float4 b = *(float4*)&Bs[k][tx * 4];
            float ar[4] = {a.x, a.y, a.z, a.w};
            float br[4] = {b.x, b.y, b.z, b.w};
#pragma unroll
            for (int i = 0; i < 4; i++)
#pragma unroll
                for (int j = 0; j < 4; j++) acc[i][j] = fmaf(ar[i], br[j], acc[i][j]);
        }
        __syncthreads();
    }
#pragma unroll
    for (int i = 0; i < 4; i++) {
        *(float4*)&QKV[(size_t)(r0 + ty * 4 + i) * TH + by * 64 + tx * 4] =
            make_float4(acc[i][0], acc[i][1], acc[i][2], acc[i][3]);
    }
}

// ---------------- per-graph 64x64 attention ----------------
__global__ __launch_bounds__(256) void attn_kernel(const float* __restrict__ QKV,
                                                   float* __restrict__ out) {
    __shared__ float Qs[16][132];
    __shared__ float sc[16][68];
    int g = blockIdx.x;
    int q0 = blockIdx.y * 16;
    int t = threadIdx.x;
    const float* base = QKV + (size_t)(g * CC) * TH;
    for (int u = t; u < 512; u += 256) {
        int i = u >> 5, cc = u & 31;
        *(float4*)&Qs[i][cc * 4] = *(const float4*)&base[(size_t)(q0 + i) * TH + cc * 4];
    }
    __syncthreads();
    {  // scores: thread (iq, j) computes rows iq, iq+4, iq+8, iq+12 vs col j
        int j = t & 63, iq = t >> 6;
        float a0 = 0, a1 = 0, a2 = 0, a3 = 0;
        const float* Krow = base + (size_t)j * TH + HH;
#pragma unroll 4
        for (int cc = 0; cc < 32; cc++) {
            float4 kv = *(const float4*)&Krow[cc * 4];
            float4 q0v = *(float4*)&Qs[iq][cc * 4];
            float4 q1v = *(float4*)&Qs[4 + iq][cc * 4];
            float4 q2v = *(float4*)&Qs[8 + iq][cc * 4];
            float4 q3v = *(float4*)&Qs[12 + iq][cc * 4];
            a0 += kv.x * q0v.x + kv.y * q0v.y + kv.z * q0v.z + kv.w * q0v.w;
            a1 += kv.x * q1v.x + kv.y * q1v.y + kv.z * q1v.z + kv.w * q1v.w;
            a2 += kv.x * q2v.x + kv.y * q2v.y + kv.z * q2v.z + kv.w * q2v.w;
            a3 += kv.x * q3v.x + kv.y * q3v.y + kv.z * q3v.z + kv.w * q3v.w;
        }
        const float scale = 0.08838834764831845f;  // 1/sqrt(128)
        sc[iq][j] = a0 * scale;
        sc[4 + iq][j] = a1 * scale;
        sc[8 + iq][j] = a2 * scale;
        sc[12 + iq][j] = a3 * scale;
    }
    __syncthreads();
    {  // softmax: 16 threads per row, 4 cols each
        int i = t >> 4, l = t & 15;
        float4 sv = *(float4*)&sc[i][l * 4];
        float m = fmaxf(fmaxf(sv.x, sv.y), fmaxf(sv.z, sv.w));
#pragma unroll
        for (int d = 1; d < 16; d <<= 1) m = fmaxf(m, __shfl_xor(m, d));
        float4 p;
        p.x = __expf(sv.x - m);
        p.y = __expf(sv.y - m);
        p.z = __expf(sv.z - m);
        p.w = __expf(sv.w - m);
        float s = p.x + p.y + p.z + p.w;
#pragma unroll
        for (int d = 1; d < 16; d <<= 1) s += __shfl_xor(s, d);
        float inv = 1.0f / s;
        p.x *= inv; p.y *= inv; p.z *= inv; p.w *= inv;
        *(float4*)&sc[i][l * 4] = p;
    }
    __syncthreads();
    {  // PV: thread (i, hq) computes out[i][hq*8 .. +8)
        int i = t >> 4, hq = t & 15;
        const float* Vbase = base + 2 * HH;
        float acc[8] = {};
        for (int j = 0; j < 64; j++) {
            float d = sc[i][j];
            float4 v0 = *(const float4*)&Vbase[(size_t)j * TH + hq * 8];
            float4 v1 = *(const float4*)&Vbase[(size_t)j * TH + hq * 8 + 4];
            acc[0] = fmaf(d, v0.x, acc[0]);
            acc[1] = fmaf(d, v0.y, acc[1]);
            acc[2] = fmaf(d, v0.z, acc[2]);
            acc[3] = fmaf(d, v0.w, acc[3]);
            acc[4] = fmaf(d, v1.x, acc[4]);
            acc[5] = fmaf(d, v1.y, acc[5]);
            acc[6] = fmaf(d, v1.z, acc[6]);
            acc[7] = fmaf(d, v1.w, acc[7]);
        }
        float* op = out + (size_t)g * (CC * HH) + (size_t)(q0 + i) * HH + hq * 8;
        *(float4*)&op[0] = make_float4(acc[0], acc[1], acc[2], acc[3]);
        *(float4*)&op[4] = make_float4(acc[4], acc[5], acc[6], acc[7]);
    }
}

extern "C" void kernel_launch(void* const* d_in, const int* in_sizes, int n_in,
                              void* d_out, int out_size, void* d_ws, size_t ws_size,
                              hipStream_t stream) {
    const float* x = (const float*)d_in[0];
    // d_in[1] = batch (unused: nodes sorted, equal graph sizes), d_in[2] = batch_size (compile-time 64)
    const int* d_rows = (const int*)d_in[3];
    const int* d_cols = (const int*)d_in[4];
    const float* d_vals = (const float*)d_in[5];
    const int* d_index = (const int*)d_in[6];
    const float* Wq = (const float*)d_in[7];
    const float* Wk = (const float*)d_in[8];
    const float* Wv = (const float*)d_in[9];
    float* out = (float*)d_out;

    char* ws = (char*)d_ws;
    size_t o = 0;
    uint* xh = (uint*)(ws + o); o += (size_t)BG * NN * (HH / 2) * 4;  // 32 MB fp16 x
    int2* epack = (int2*)(ws + o); o += (size_t)BG * NNZE * 8;        // 16 MB
    int* cnt_blk = (int*)(ws + o); o += (size_t)BG * 4 * MM * 4;      // 2 MB
    int* off_row_blk = (int*)(ws + o); o += (size_t)BG * 4 * MM * 4;  // 2 MB
    int* end_pos = (int*)(ws + o); o += (size_t)BG * MM * 4;
    int* cnt_clu_blk = (int*)(ws + o); o += (size_t)BG * 4 * CC * 4;
    int* row_edge_off = (int*)(ws + o); o += (size_t)BG * (MM + 1) * 4;
    int* cnt_clu = (int*)(ws + o); o += (size_t)BG * CC * 4;
    int* off_clu = (int*)(ws + o); o += (size_t)BG * CC * 4;
    float* xdec = (float*)(ws + o); o += (size_t)BG * CC * TH * 4;
    float* QKV = (float*)(ws + o); o += (size_t)BG * CC * TH * 4;

    prep_count_kernel<<<BG * 4, 1024, 0, stream>>>(d_rows, d_index, cnt_blk, cnt_clu_blk);
    prep_scan_kernel<<<BG, 1024, 0, stream>>>(d_index, cnt_blk, cnt_clu_blk,
                                              cnt_clu, off_clu, row_edge_off,
                                              off_row_blk, end_pos);
    prep_bin_kernel<<<BG * 4, 1024, 0, stream>>>(d_rows, d_cols, d_vals,
                                                 off_row_blk, end_pos, epack);
    // cvt_x LAST before spmm: XCD-aligned writes leave xh resident in the right L2s
    cvt_x_kernel<<<BG * NN * HH / 8 / 256, 256, 0, stream>>>(x, xh);
    spmm_pool_kernel<<<BG * CC, 64, 0, stream>>>(xh, cnt_clu, off_clu, row_edge_off,
                                                 epack, xdec);
    qkv_kernel<<<dim3(64, 6), 256, 0, stream>>>(xdec, Wq, Wk, Wv, QKV);
    attn_kernel<<<dim3(BG, 4), 256, 0, stream>>>(QKV, out);
}

// Round 12
// 271.410 us; speedup vs baseline: 1.1758x; 1.0052x over previous
//
#include <hip/hip_runtime.h>
#include <hip/hip_fp16.h>

#define BG 64
#define NN 2048
#define MM 2048
#define CC 64
#define HH 128
#define NNZE 32768
#define TH 384  // 3*H

typedef float f4v __attribute__((ext_vector_type(4)));  // nt-builtin rejects HIP float4

// ---------------- x (fp32) -> xh (fp16 RNE), packed 2 features per uint ----------------
// XCD-swizzled to match spmm's graph->XCD mapping (graph g on XCD g>>3) and launched
// immediately before spmm. NT reads: the 64 MB x stream must not evict the 32 MB of xh
// this kernel writes (R10 showed zero xh survived with cached reads -> spmm FETCH 52 MB
// = full compulsory; R8 variant with an nt-kept-clean L2 retained ~18 MB).
__global__ __launch_bounds__(256) void cvt_x_kernel(const float* __restrict__ x,
                                                    uint* __restrict__ xh) {
    int bid = blockIdx.x;                       // 8192 blocks, 128 per graph
    int j = bid >> 3;                           // 0..1023
    int g = ((bid & 7) << 3) + (j >> 7);        // XCD = bid&7 = g>>3
    int chunk = j & 127;
    int tid = g * 32768 + chunk * 256 + threadIdx.x;  // group-of-8-floats index
    const f4v* x4 = (const f4v*)x;
    f4v a = __builtin_nontemporal_load(&x4[2 * tid]);
    f4v b = __builtin_nontemporal_load(&x4[2 * tid + 1]);
    __half2 h0 = __float22half2_rn(make_float2(a.x, a.y));
    __half2 h1 = __float22half2_rn(make_float2(a.z, a.w));
    __half2 h2 = __float22half2_rn(make_float2(b.x, b.y));
    __half2 h3 = __float22half2_rn(make_float2(b.z, b.w));
    uint4 o;
    o.x = *(uint*)&h0;
    o.y = *(uint*)&h1;
    o.z = *(uint*)&h2;
    o.w = *(uint*)&h3;
    ((uint4*)xh)[tid] = o;
}

// ---------------- prep phase A: per-(graph, quarter) counting, 256 blocks ----------------
__global__ __launch_bounds__(1024) void prep_count_kernel(const int* __restrict__ d_rows,
                                                          const int* __restrict__ d_index,
                                                          int* __restrict__ cnt_blk,
                                                          int* __restrict__ cnt_clu_blk) {
    __shared__ int cnt_row_s[MM];
    __shared__ int cnt_clu_s[CC];
    int gb = blockIdx.x;  // g*4 + b
    int g = gb >> 2, b = gb & 3;
    int t = threadIdx.x;
    cnt_row_s[t] = 0;
    cnt_row_s[t + 1024] = 0;
    if (t < CC) cnt_clu_s[t] = 0;
    __syncthreads();
    const int* rows_g = d_rows + ((size_t)g << 15) + (b << 13);
#pragma unroll
    for (int it = 0; it < 8; it++) atomicAdd(&cnt_row_s[rows_g[it * 1024 + t]], 1);
    if (t < 512) atomicAdd(&cnt_clu_s[d_index[(g << 11) + (b << 9) + t]], 1);
    __syncthreads();
    int* cb = cnt_blk + (size_t)gb * MM;
    cb[t] = cnt_row_s[t];
    cb[t + 1024] = cnt_row_s[t + 1024];
    if (t < CC) cnt_clu_blk[gb * CC + t] = cnt_clu_s[t];
}

// ---------------- prep phase B: per-graph scans, rlist, per-block base offsets ----------------
__global__ __launch_bounds__(1024) void prep_scan_kernel(const int* __restrict__ d_index,
                                                         const int* __restrict__ cnt_blk,
                                                         const int* __restrict__ cnt_clu_blk,
                                                         int* __restrict__ cnt_clu_g,
                                                         int* __restrict__ off_clu_g,
                                                         int* __restrict__ row_edge_off_g,
                                                         int* __restrict__ off_row_blk,
                                                         int* __restrict__ end_pos) {
    __shared__ int cnt_clu_s[CC], off_clu_s[CC], fill_clu_s[CC];
    __shared__ int rlist_s[MM];
    __shared__ int rowtot_s[MM];
    __shared__ int blk1_s[MM], blk2_s[MM], blk3_s[MM];
    __shared__ int off_row_s[MM];
    __shared__ int wsum[16];
    int g = blockIdx.x, t = threadIdx.x;
    int lane = t & 63, w = t >> 6;

    // row totals + per-block prefixes (coalesced)
    const int* cb = cnt_blk + ((size_t)g << 2) * MM;
    for (int r = t; r < MM; r += 1024) {
        int c0 = cb[r], c1 = cb[MM + r], c2 = cb[2 * MM + r], c3 = cb[3 * MM + r];
        blk1_s[r] = c0;
        blk2_s[r] = c0 + c1;
        blk3_s[r] = c0 + c1 + c2;
        rowtot_s[r] = c0 + c1 + c2 + c3;
    }
    // cluster counts + scan (wave 0)
    if (t < CC) {
        const int* ccb = cnt_clu_blk + (g << 2) * CC;
        int v = ccb[t] + ccb[CC + t] + ccb[2 * CC + t] + ccb[3 * CC + t];
        cnt_clu_s[t] = v;
        fill_clu_s[t] = 0;
        int incl = v;
#pragma unroll
        for (int d = 1; d < 64; d <<= 1) {
            int u = __shfl_up(incl, d);
            if (t >= d) incl += u;
        }
        off_clu_s[t] = incl - v;
        cnt_clu_g[(g << 6) + t] = v;
        off_clu_g[(g << 6) + t] = incl - v;
    }
    int idx0 = d_index[(g << 11) + t];
    int idx1 = d_index[(g << 11) + t + 1024];
    __syncthreads();

    // rlist: rows in cluster-major order
    {
        int s0 = atomicAdd(&fill_clu_s[idx0], 1);
        rlist_s[off_clu_s[idx0] + s0] = t;
        int s1 = atomicAdd(&fill_clu_s[idx1], 1);
        rlist_s[off_clu_s[idx1] + s1] = t + 1024;
    }
    __syncthreads();

    // cluster-major scan of row totals (thread t owns j=2t, 2t+1)
    int r0 = rlist_s[2 * t], r1 = rlist_s[2 * t + 1];
    int c0 = rowtot_s[r0], c1 = rowtot_s[r1];
    int s = c0 + c1;
    int incl = s;
#pragma unroll
    for (int d = 1; d < 64; d <<= 1) {
        int u = __shfl_up(incl, d);
        if (lane >= d) incl += u;
    }
    if (lane == 63) wsum[w] = incl;
    __syncthreads();
    if (t < 16) {
        int v = wsum[t], iv = v;
#pragma unroll
        for (int d = 1; d < 16; d <<= 1) {
            int u = __shfl_up(iv, d);
            if (t >= d) iv += u;
        }
        wsum[t] = iv - v;  // exclusive
    }
    __syncthreads();
    {
        int base = wsum[w] + incl - s;
        int* reo = row_edge_off_g + g * (MM + 1);
        reo[2 * t] = base;
        reo[2 * t + 1] = base + c0;
        off_row_s[r0] = base;
        off_row_s[r1] = base + c0;
        if (t == 0) reo[MM] = NNZE;
    }
    __syncthreads();

    // emit per-(block,row) bases + end positions (coalesced by r)
    int* ob = off_row_blk + ((size_t)g << 2) * MM;
    int* epp = end_pos + (size_t)g * MM;
    for (int r = t; r < MM; r += 1024) {
        int orr = off_row_s[r];
        ob[r] = orr;
        ob[MM + r] = orr + blk1_s[r];
        ob[2 * MM + r] = orr + blk2_s[r];
        ob[3 * MM + r] = orr + blk3_s[r];
        epp[r] = orr + rowtot_s[r];
    }
}

// ---------------- prep phase C: per-(graph, quarter) binning, 256 blocks ----------------
// each block owns pre-reserved sub-ranges -> LDS-only slot allocation; flag is position-based.
// Plain (write-back) stores: nt-hint on scattered 8B stores caused 4x write amplification (R9).
__global__ __launch_bounds__(1024) void prep_bin_kernel(const int* __restrict__ d_rows,
                                                        const int* __restrict__ d_cols,
                                                        const float* __restrict__ d_vals,
                                                        const int* __restrict__ off_row_blk,
                                                        const int* __restrict__ end_pos,
                                                        int2* __restrict__ epack) {
    __shared__ int off_s[MM];
    __shared__ int end_s[MM];
    __shared__ int fill_s[MM];
    int gb = blockIdx.x;
    int g = gb >> 2, b = gb & 3;
    int t = threadIdx.x;
    const int* ob = off_row_blk + (size_t)gb * MM;
    const int* epp = end_pos + (size_t)g * MM;
    off_s[t] = ob[t];
    off_s[t + 1024] = ob[t + 1024];
    end_s[t] = epp[t];
    end_s[t + 1024] = epp[t + 1024];
    fill_s[t] = 0;
    fill_s[t + 1024] = 0;
    __syncthreads();
    const int* rows_g = d_rows + ((size_t)g << 15) + (b << 13);
    const int* cols_g = d_cols + ((size_t)g << 15) + (b << 13);
    const float* vals_g = d_vals + ((size_t)g << 15) + (b << 13);
    int2* epg = epack + ((size_t)g << 15);
#pragma unroll
    for (int it = 0; it < 8; it++) {
        int e = it * 1024 + t;
        int r = rows_g[e];
        int slot = atomicAdd(&fill_s[r], 1);
        int pos = off_s[r] + slot;
        int flag = (pos == end_s[r] - 1) ? (int)0x80000000 : 0;
        epg[pos] = make_int2(cols_g[e] | flag, __float_as_int(vals_g[e]));
    }
}

// ---------------- fused SpMM + mean/max/sum pooling, one wave64 per cluster, fp16 x ----------------
// lane h handles features 2h,2h+1: one uint gather per lane -> 256 B/row coalesced (R6 shape:
// 64-thr blocks measured 60us vs 256-thr 93us -- TA-throughput-bound, more waves don't help)
__global__ __launch_bounds__(64) void spmm_pool_kernel(const uint* __restrict__ xh,
                                                       const int* __restrict__ cnt_clu,
                                                       const int* __restrict__ off_clu,
                                                       const int* __restrict__ row_edge_off,
                                                       const int2* __restrict__ epack,
                                                       float* __restrict__ xdec) {
    // XCD-aware swizzle: bid&7 -> XCD, graphs [8q, 8q+7] on XCD q (matches cvt_x)
    int bid = blockIdx.x;
    int l = bid >> 3;
    int g = ((bid & 7) << 3) + (l >> 6);
    int c = l & 63;
    int h = threadIdx.x;  // 0..63
    int gc = (g << 6) + c;
    int rcnt = cnt_clu[gc];
    int j0 = off_clu[gc];
    const int* reo = row_edge_off + g * (MM + 1) + j0;
    int ebase = reo[0];
    int etot = reo[rcnt] - ebase;
    const long long* ep = (const long long*)(epack + ((size_t)g << 15)) + ebase;
    const uint* xg = xh + ((size_t)g << 17);  // g*N*(H/2) uints
    float2 coef = make_float2(0.f, 0.f), sum = make_float2(0.f, 0.f);
    float2 mx = make_float2(-__builtin_inff(), -__builtin_inff());
    int e = 0;
    for (; e + 16 <= etot; e += 16) {
        long long q[16];
#pragma unroll
        for (int k = 0; k < 16; k++) q[k] = __builtin_nontemporal_load(&ep[e + k]);
        uint xv[16];
#pragma unroll
        for (int k = 0; k < 16; k++)
            xv[k] = xg[(((uint)(int)q[k] & 0x7FFFFFFFu) << 6) + h];
#pragma unroll
        for (int k = 0; k < 16; k++) {
            float v = __int_as_float((int)(q[k] >> 32));
            float2 f = __half22float2(*(__half2*)&xv[k]);
            coef.x = fmaf(v, f.x, coef.x);
            coef.y = fmaf(v, f.y, coef.y);
            if ((int)q[k] < 0) {  // wave-uniform (all lanes see same edge)
                sum.x += coef.x; sum.y += coef.y;
                mx.x = fmaxf(mx.x, coef.x); mx.y = fmaxf(mx.y, coef.y);
                coef.x = 0.f; coef.y = 0.f;
            }
        }
    }
    for (; e < etot; e++) {
        long long q = ep[e];
        uint xv = xg[(((uint)(int)q & 0x7FFFFFFFu) << 6) + h];
        float v = __int_as_float((int)(q >> 32));
        float2 f = __half22float2(*(__half2*)&xv);
        coef.x = fmaf(v, f.x, coef.x);
        coef.y = fmaf(v, f.y, coef.y);
        if ((int)q < 0) {
            sum.x += coef.x; sum.y += coef.y;
            mx.x = fmaxf(mx.x, coef.x); mx.y = fmaxf(mx.y, coef.y);
            coef.x = 0.f; coef.y = 0.f;
        }
    }
    // rows with zero edges contribute coef==0 to the max
    int az = 0;
    for (int j = h; j < rcnt; j += 64) az |= (reo[j + 1] == reo[j]);
    if (__ballot(az) != 0ULL) {
        mx.x = fmaxf(mx.x, 0.f);
        mx.y = fmaxf(mx.y, 0.f);
    }
    float inv = 1.f / (float)(rcnt > 0 ? rcnt : 1);
    float* xd = xdec + (size_t)gc * TH;
    *(float2*)&xd[2 * h] = make_float2(sum.x * inv, sum.y * inv);
    *(float2*)&xd[HH + 2 * h] = mx;
    *(float2*)&xd[2 * HH + 2 * h] = sum;
}

// ---------------- QKV projection: [4096,384] @ [384,384] -> QKV [4096,384] ----------------
__global__ __launch_bounds__(256) void qkv_kernel(const float* __restrict__ xdec,
                                                  const float* __restrict__ Wq,
                                                  const float* __restrict__ Wk,
                                                  const float* __restrict__ Wv,
                                                  float* __restrict__ QKV) {
    __shared__ float As[16][68];  // A^T tile: [k][row], pad avoids bank conflicts
    __shared__ float Bs[16][64];  // [k][col]
    int bx = blockIdx.x, by = blockIdx.y;
    int t = threadIdx.x;
    int tx = t & 15, ty = t >> 4;
    const float* W = (by < 2) ? Wq : (by < 4) ? Wk : Wv;
    int cbase = (by & 1) * 64;
    int r0 = bx * 64;
    float acc[4][4] = {};
    int lrow = t >> 2, lk4 = (t & 3) * 4;
    for (int k0 = 0; k0 < TH; k0 += 16) {
        float4 av = *(const float4*)&xdec[(size_t)(r0 + lrow) * TH + k0 + lk4];
        As[lk4][lrow] = av.x;
        As[lk4 + 1][lrow] = av.y;
        As[lk4 + 2][lrow] = av.z;
        As[lk4 + 3][lrow] = av.w;
        *(float4*)&Bs[ty][tx * 4] = *(const float4*)&W[(size_t)(k0 + ty) * HH + cbase + tx * 4];
        __syncthreads();
#pragma unroll
        for (int k = 0; k < 16; k++) {
            float4 a = *(float4*)&As[k][ty * 4];
            float4 b = *(float4*)&Bs[k][tx * 4];
            float ar[4] = {a.x, a.y, a.z, a.w};
            float br[4] = {b.x, b.y, b.z, b.w};
#pragma unroll
            for (int i = 0; i < 4; i++)
#pragma unroll
                for (int j = 0; j < 4; j++) acc[i][j] = fmaf(ar[i], br[j], acc[i][j]);
        }
        __syncthreads();
    }
#pragma unroll
    for (int i = 0; i < 4; i++) {
        *(float4*)&QKV[(size_t)(r0 + ty * 4 + i) * TH + by * 64 + tx * 4] =
            make_float4(acc[i][0], acc[i][1], acc[i][2], acc[i][3]);
    }
}

// ---------------- per-graph 64x64 attention ----------------
__global__ __launch_bounds__(256) void attn_kernel(const float* __restrict__ QKV,
                                                   float* __restrict__ out) {
    __shared__ float Qs[16][132];
    __shared__ float sc[16][68];
    int g = blockIdx.x;
    int q0 = blockIdx.y * 16;
    int t = threadIdx.x;
    const float* base = QKV + (size_t)(g * CC) * TH;
    for (int u = t; u < 512; u += 256) {
        int i = u >> 5, cc = u & 31;
        *(float4*)&Qs[i][cc * 4] = *(const float4*)&base[(size_t)(q0 + i) * TH + cc * 4];
    }
    __syncthreads();
    {  // scores: thread (iq, j) computes rows iq, iq+4, iq+8, iq+12 vs col j
        int j = t & 63, iq = t >> 6;
        float a0 = 0, a1 = 0, a2 = 0, a3 = 0;
        const float* Krow = base + (size_t)j * TH + HH;
#pragma unroll 4
        for (int cc = 0; cc < 32; cc++) {
            float4 kv = *(const float4*)&Krow[cc * 4];
            float4 q0v = *(float4*)&Qs[iq][cc * 4];
            float4 q1v = *(float4*)&Qs[4 + iq][cc * 4];
            float4 q2v = *(float4*)&Qs[8 + iq][cc * 4];
            float4 q3v = *(float4*)&Qs[12 + iq][cc * 4];
            a0 += kv.x * q0v.x + kv.y * q0v.y + kv.z * q0v.z + kv.w * q0v.w;
            a1 += kv.x * q1v.x + kv.y * q1v.y + kv.z * q1v.z + kv.w * q1v.w;
            a2 += kv.x * q2v.x + kv.y * q2v.y + kv.z * q2v.z + kv.w * q2v.w;
            a3 += kv.x * q3v.x + kv.y * q3v.y + kv.z * q3v.z + kv.w * q3v.w;
        }
        const float scale = 0.08838834764831845f;  // 1/sqrt(128)
        sc[iq][j] = a0 * scale;
        sc[4 + iq][j] = a1 * scale;
        sc[8 + iq][j] = a2 * scale;
        sc[12 + iq][j] = a3 * scale;
    }
    __syncthreads();
    {  // softmax: 16 threads per row, 4 cols each
        int i = t >> 4, l = t & 15;
        float4 sv = *(float4*)&sc[i][l * 4];
        float m = fmaxf(fmaxf(sv.x, sv.y), fmaxf(sv.z, sv.w));
#pragma unroll
        for (int d = 1; d < 16; d <<= 1) m = fmaxf(m, __shfl_xor(m, d));
        float4 p;
        p.x = __expf(sv.x - m);
        p.y = __expf(sv.y - m);
        p.z = __expf(sv.z - m);
        p.w = __expf(sv.w - m);
        float s = p.x + p.y + p.z + p.w;
#pragma unroll
        for (int d = 1; d < 16; d <<= 1) s += __shfl_xor(s, d);
        float inv = 1.0f / s;
        p.x *= inv; p.y *= inv; p.z *= inv; p.w *= inv;
        *(float4*)&sc[i][l * 4] = p;
    }
    __syncthreads();
    {  // PV: thread (i, hq) computes out[i][hq*8 .. +8)
        int i = t >> 4, hq = t & 15;
        const float* Vbase = base + 2 * HH;
        float acc[8] = {};
        for (int j = 0; j < 64; j++) {
            float d = sc[i][j];
            float4 v0 = *(const float4*)&Vbase[(size_t)j * TH + hq * 8];
            float4 v1 = *(const float4*)&Vbase[(size_t)j * TH + hq * 8 + 4];
            acc[0] = fmaf(d, v0.x, acc[0]);
            acc[1] = fmaf(d, v0.y, acc[1]);
            acc[2] = fmaf(d, v0.z, acc[2]);
            acc[3] = fmaf(d, v0.w, acc[3]);
            acc[4] = fmaf(d, v1.x, acc[4]);
            acc[5] = fmaf(d, v1.y, acc[5]);
            acc[6] = fmaf(d, v1.z, acc[6]);
            acc[7] = fmaf(d, v1.w, acc[7]);
        }
        float* op = out + (size_t)g * (CC * HH) + (size_t)(q0 + i) * HH + hq * 8;
        *(float4*)&op[0] = make_float4(acc[0], acc[1], acc[2], acc[3]);
        *(float4*)&op[4] = make_float4(acc[4], acc[5], acc[6], acc[7]);
    }
}

extern "C" void kernel_launch(void* const* d_in, const int* in_sizes, int n_in,
                              void* d_out, int out_size, void* d_ws, size_t ws_size,
                              hipStream_t stream) {
    const float* x = (const float*)d_in[0];
    // d_in[1] = batch (unused: nodes sorted, equal graph sizes), d_in[2] = batch_size (compile-time 64)
    const int* d_rows = (const int*)d_in[3];
    const int* d_cols = (const int*)d_in[4];
    const float* d_vals = (const float*)d_in[5];
    const int* d_index = (const int*)d_in[6];
    const float* Wq = (const float*)d_in[7];
    const float* Wk = (const float*)d_in[8];
    const float* Wv = (const float*)d_in[9];
    float* out = (float*)d_out;

    char* ws = (char*)d_ws;
    size_t o = 0;
    uint* xh = (uint*)(ws + o); o += (size_t)BG * NN * (HH / 2) * 4;  // 32 MB fp16 x
    int2* epack = (int2*)(ws + o); o += (size_t)BG * NNZE * 8;        // 16 MB
    int* cnt_blk = (int*)(ws + o); o += (size_t)BG * 4 * MM * 4;      // 2 MB
    int* off_row_blk = (int*)(ws + o); o += (size_t)BG * 4 * MM * 4;  // 2 MB
    int* end_pos = (int*)(ws + o); o += (size_t)BG * MM * 4;
    int* cnt_clu_blk = (int*)(ws + o); o += (size_t)BG * 4 * CC * 4;
    int* row_edge_off = (int*)(ws + o); o += (size_t)BG * (MM + 1) * 4;
    int* cnt_clu = (int*)(ws + o); o += (size_t)BG * CC * 4;
    int* off_clu = (int*)(ws + o); o += (size_t)BG * CC * 4;
    float* xdec = (float*)(ws + o); o += (size_t)BG * CC * TH * 4;
    float* QKV = (float*)(ws + o); o += (size_t)BG * CC * TH * 4;

    prep_count_kernel<<<BG * 4, 1024, 0, stream>>>(d_rows, d_index, cnt_blk, cnt_clu_blk);
    prep_scan_kernel<<<BG, 1024, 0, stream>>>(d_index, cnt_blk, cnt_clu_blk,
                                              cnt_clu, off_clu, row_edge_off,
                                              off_row_blk, end_pos);
    prep_bin_kernel<<<BG * 4, 1024, 0, stream>>>(d_rows, d_cols, d_vals,
                                                 off_row_blk, end_pos, epack);
    // cvt_x LAST before spmm: XCD-aligned nt-read/cached-write leaves xh resident in L2
    cvt_x_kernel<<<BG * NN * HH / 8 / 256, 256, 0, stream>>>(x, xh);
    spmm_pool_kernel<<<BG * CC, 64, 0, stream>>>(xh, cnt_clu, off_clu, row_edge_off,
                                                 epack, xdec);
    qkv_kernel<<<dim3(64, 6), 256, 0, stream>>>(xdec, Wq, Wk, Wv, QKV);
    attn_kernel<<<dim3(BG, 4), 256, 0, stream>>>(QKV, out);
}